// Round 1
// baseline (370.777 us; speedup 1.0000x reference)
//
#include <hip/hip_runtime.h>
#include <hip/hip_bf16.h>

// GCN regressor: 3x GCNConv(64->64, normalize=False) + mean-pool + MLP(64->32->16->1)
// Strategy:
//  - Build CSR-by-dst once per call (deg histogram -> block scan -> fill). Reused 3x.
//  - gemm64: pure x@W (64x64), W column in 64 VGPRs/lane, row broadcast via __shfl.
//  - agg: per-node 16-lane group gathers h[src]*ew, register-accumulates (no atomics),
//         fused relu(acc + bias) epilogue.
//  - pool: sorted-batch run-length accumulation, few atomics.
//  - head: single-block MLP.

#define HID 64

__global__ __launch_bounds__(256) void deg_kernel(const int* __restrict__ ei,
                                                  int* __restrict__ deg, int E) {
    int e = blockIdx.x * 256 + threadIdx.x;
    if (e < E) atomicAdd(&deg[ei[E + e]], 1);   // row 1 of edge_index = dst
}

__global__ __launch_bounds__(256) void scan1_kernel(const int* __restrict__ deg,
                                                    int* __restrict__ offs,
                                                    int* __restrict__ bsum, int N) {
    __shared__ int sh[256];
    int t = threadIdx.x;
    int i = blockIdx.x * 256 + t;
    int v = (i < N) ? deg[i] : 0;
    sh[t] = v;
    __syncthreads();
    #pragma unroll
    for (int d = 1; d < 256; d <<= 1) {
        int add = (t >= d) ? sh[t - d] : 0;
        __syncthreads();
        sh[t] += add;
        __syncthreads();
    }
    if (i < N) offs[i] = sh[t] - v;            // exclusive within block
    if (t == 255) bsum[blockIdx.x] = sh[255];  // block total
}

__global__ __launch_bounds__(256) void scan2_kernel(int* __restrict__ bsum, int nb) {
    __shared__ int sh[256];
    int t = threadIdx.x;
    int v = (t < nb) ? bsum[t] : 0;
    sh[t] = v;
    __syncthreads();
    #pragma unroll
    for (int d = 1; d < 256; d <<= 1) {
        int add = (t >= d) ? sh[t - d] : 0;
        __syncthreads();
        sh[t] += add;
        __syncthreads();
    }
    if (t < nb) bsum[t] = sh[t] - v;           // exclusive over blocks
}

__global__ __launch_bounds__(256) void scan3_kernel(int* __restrict__ offs,
                                                    const int* __restrict__ bsum,
                                                    int N, int E) {
    int i = blockIdx.x * 256 + threadIdx.x;
    if (i < N) offs[i] += bsum[blockIdx.x];
    if (i == 0) offs[N] = E;
}

__global__ __launch_bounds__(256) void copy_kernel(const int* __restrict__ a,
                                                   int* __restrict__ b, int n) {
    int i = blockIdx.x * 256 + threadIdx.x;
    if (i < n) b[i] = a[i];
}

__global__ __launch_bounds__(256) void fill_kernel(const int* __restrict__ ei,
                                                   const float* __restrict__ ew,
                                                   int* __restrict__ cursor,
                                                   int* __restrict__ csr_src,
                                                   float* __restrict__ csr_ew, int E) {
    int e = blockIdx.x * 256 + threadIdx.x;
    if (e < E) {
        int d = ei[E + e];
        int slot = atomicAdd(&cursor[d], 1);
        csr_src[slot] = ei[e];
        csr_ew[slot] = ew[e];
    }
}

// out[r][j] = sum_k in[r][k] * W[k][j]   (64x64 W; lane j holds W column j in regs)
__global__ __launch_bounds__(256) void gemm64_kernel(const float* __restrict__ in,
                                                     const float* __restrict__ W,
                                                     float* __restrict__ out, int nrows) {
    const int lane = threadIdx.x & 63;
    const int gwave = (blockIdx.x * blockDim.x + threadIdx.x) >> 6;
    const int nwaves = (gridDim.x * blockDim.x) >> 6;
    float wcol[64];
    #pragma unroll
    for (int k = 0; k < 64; ++k) wcol[k] = W[k * 64 + lane];
    for (int r = gwave; r < nrows; r += nwaves) {
        float xv = in[(size_t)r * 64 + lane];
        float acc = 0.f;
        #pragma unroll
        for (int k = 0; k < 64; ++k)
            acc = fmaf(__shfl(xv, k, 64), wcol[k], acc);
        out[(size_t)r * 64 + lane] = acc;
    }
}

// Per-node CSR aggregation: 16 lanes/node, 4 channels each (float4).
// out[n] = relu( sum_{e in CSR(n)} ew[e]*h[src[e]] + bias )
__global__ __launch_bounds__(256) void agg_kernel(const float* __restrict__ h,
                                                  const int* __restrict__ csr_src,
                                                  const float* __restrict__ csr_ew,
                                                  const int* __restrict__ offs,
                                                  const float* __restrict__ bias,
                                                  float* __restrict__ out, int N) {
    int g = (blockIdx.x * 256 + threadIdx.x) >> 4;   // node
    int l = threadIdx.x & 15;                        // lane in group: channels 4l..4l+3
    if (g >= N) return;
    int e0 = offs[g], e1 = offs[g + 1];
    float4 acc = make_float4(0.f, 0.f, 0.f, 0.f);
    for (int e = e0; e < e1; ++e) {
        int s = csr_src[e];
        float w = csr_ew[e];
        const float4 v = *reinterpret_cast<const float4*>(h + (size_t)s * 64 + l * 4);
        acc.x = fmaf(w, v.x, acc.x);
        acc.y = fmaf(w, v.y, acc.y);
        acc.z = fmaf(w, v.z, acc.z);
        acc.w = fmaf(w, v.w, acc.w);
    }
    const float4 b4 = *reinterpret_cast<const float4*>(bias + l * 4);
    float4 r;
    r.x = fmaxf(acc.x + b4.x, 0.f);
    r.y = fmaxf(acc.y + b4.y, 0.f);
    r.z = fmaxf(acc.z + b4.z, 0.f);
    r.w = fmaxf(acc.w + b4.w, 0.f);
    *reinterpret_cast<float4*>(out + (size_t)g * 64 + l * 4) = r;
}

// Mean-pool stage 1: sorted batch -> register run-length accumulate, atomic flush.
__global__ __launch_bounds__(256) void pool_kernel(const float* __restrict__ a,
                                                   const int* __restrict__ batch,
                                                   float* __restrict__ sums,
                                                   float* __restrict__ cnts, int N) {
    int c = threadIdx.x & 63;
    int sub = threadIdx.x >> 6;   // 0..3
    int chunk = (N + gridDim.x - 1) / gridDim.x;
    int start = blockIdx.x * chunk;
    int end = min(N, start + chunk);
    int curg = -1;
    float acc = 0.f, cacc = 0.f;
    for (int n = start + sub; n < end; n += 4) {
        int g = batch[n];
        if (g != curg) {
            if (curg >= 0) {
                atomicAdd(&sums[curg * 64 + c], acc);
                if (c == 0) atomicAdd(&cnts[curg], cacc);
            }
            curg = g; acc = 0.f; cacc = 0.f;
        }
        acc += a[(size_t)n * 64 + c];
        cacc += 1.f;
    }
    if (curg >= 0) {
        atomicAdd(&sums[curg * 64 + c], acc);
        if (c == 0) atomicAdd(&cnts[curg], cacc);
    }
}

// MLP head: pooled[G][64] -> relu(@lw1 64x32) -> relu(@lw2 32x16) -> @lw3 16x1
__global__ __launch_bounds__(256) void head_kernel(const float* __restrict__ sums,
                                                   const float* __restrict__ cnts,
                                                   const float* __restrict__ lw1,
                                                   const float* __restrict__ lb1,
                                                   const float* __restrict__ lw2,
                                                   const float* __restrict__ lb2,
                                                   const float* __restrict__ lw3,
                                                   const float* __restrict__ lb3,
                                                   float* __restrict__ out, int G) {
    __shared__ float pooled[64 * 64];
    __shared__ float z1[64 * 32];
    __shared__ float z2[64 * 16];
    int tid = threadIdx.x;
    for (int i = tid; i < G * 64; i += 256) {
        int g = i >> 6;
        float cn = cnts[g];
        cn = (cn < 1.f) ? 1.f : cn;
        pooled[i] = sums[i] / cn;
    }
    __syncthreads();
    for (int i = tid; i < G * 32; i += 256) {
        int g = i >> 5, j = i & 31;
        float acc = lb1[j];
        #pragma unroll
        for (int k = 0; k < 64; ++k) acc = fmaf(pooled[g * 64 + k], lw1[k * 32 + j], acc);
        z1[i] = fmaxf(acc, 0.f);
    }
    __syncthreads();
    for (int i = tid; i < G * 16; i += 256) {
        int g = i >> 4, j = i & 15;
        float acc = lb2[j];
        #pragma unroll
        for (int k = 0; k < 32; ++k) acc = fmaf(z1[g * 32 + k], lw2[k * 16 + j], acc);
        z2[i] = fmaxf(acc, 0.f);
    }
    __syncthreads();
    if (tid < G) {
        float acc = lb3[0];
        #pragma unroll
        for (int k = 0; k < 16; ++k) acc = fmaf(z2[tid * 16 + k], lw3[k], acc);
        out[tid] = acc;
    }
}

static inline size_t align256(size_t x) { return (x + 255) & ~(size_t)255; }

extern "C" void kernel_launch(void* const* d_in, const int* in_sizes, int n_in,
                              void* d_out, int out_size, void* d_ws, size_t ws_size,
                              hipStream_t stream) {
    const float* x     = (const float*)d_in[0];
    const int*   ei    = (const int*)d_in[1];     // (2,E): [0..E)=src, [E..2E)=dst
    const float* ew    = (const float*)d_in[2];
    const int*   batch = (const int*)d_in[3];
    const float* W1 = (const float*)d_in[4];
    const float* b1 = (const float*)d_in[5];
    const float* W2 = (const float*)d_in[6];
    const float* b2 = (const float*)d_in[7];
    const float* W3 = (const float*)d_in[8];
    const float* b3 = (const float*)d_in[9];
    const float* lw1 = (const float*)d_in[10];
    const float* lb1 = (const float*)d_in[11];
    const float* lw2 = (const float*)d_in[12];
    const float* lb2 = (const float*)d_in[13];
    const float* lw3 = (const float*)d_in[14];
    const float* lb3 = (const float*)d_in[15];
    float* out = (float*)d_out;

    const int N = in_sizes[0] / 64;
    const int E = in_sizes[2];
    const int G = out_size;

    // Workspace carve
    char* w = (char*)d_ws;
    size_t off = 0;
    auto carve = [&](size_t bytes) -> void* {
        void* p = w + off;
        off = align256(off + bytes);
        return p;
    };
    float* bufA   = (float*)carve((size_t)N * 64 * 4);
    float* bufB   = (float*)carve((size_t)N * 64 * 4);
    int*   csrS   = (int*)carve((size_t)E * 4);
    float* csrW   = (float*)carve((size_t)E * 4);
    int*   deg    = (int*)carve((size_t)N * 4);
    int*   offs   = (int*)carve((size_t)(N + 1) * 4);
    int*   cursor = (int*)carve((size_t)N * 4);
    int*   bsum   = (int*)carve(256 * 4);
    float* sums   = (float*)carve((size_t)G * 64 * 4);
    float* cnts   = (float*)carve((size_t)G * 4);
    (void)ws_size; (void)n_in;

    const int EB = (E + 255) / 256;        // edge blocks
    const int NB = (N + 255) / 256;        // node blocks (<=256 for scan2)

    // ---- CSR build (once; dst reused for all 3 layers) ----
    hipMemsetAsync(deg, 0, (size_t)N * 4, stream);
    hipMemsetAsync(sums, 0, (size_t)G * 64 * 4, stream);
    hipMemsetAsync(cnts, 0, (size_t)G * 4, stream);
    deg_kernel<<<EB, 256, 0, stream>>>(ei, deg, E);
    scan1_kernel<<<NB, 256, 0, stream>>>(deg, offs, bsum, N);
    scan2_kernel<<<1, 256, 0, stream>>>(bsum, NB);
    scan3_kernel<<<NB, 256, 0, stream>>>(offs, bsum, N, E);
    copy_kernel<<<NB, 256, 0, stream>>>(offs, cursor, N);
    fill_kernel<<<EB, 256, 0, stream>>>(ei, ew, cursor, csrS, csrW, E);

    const int GEMM_BLOCKS = 1024;
    const int AGG_BLOCKS = (N * 16 + 255) / 256;

    // ---- layer 1 ----
    gemm64_kernel<<<GEMM_BLOCKS, 256, 0, stream>>>(x, W1, bufA, N);
    agg_kernel<<<AGG_BLOCKS, 256, 0, stream>>>(bufA, csrS, csrW, offs, b1, bufB, N);
    // ---- layer 2 ----
    gemm64_kernel<<<GEMM_BLOCKS, 256, 0, stream>>>(bufB, W2, bufA, N);
    agg_kernel<<<AGG_BLOCKS, 256, 0, stream>>>(bufA, csrS, csrW, offs, b2, bufB, N);
    // ---- layer 3 ----
    gemm64_kernel<<<GEMM_BLOCKS, 256, 0, stream>>>(bufB, W3, bufA, N);
    agg_kernel<<<AGG_BLOCKS, 256, 0, stream>>>(bufA, csrS, csrW, offs, b3, bufB, N);

    // ---- pool + head ----
    pool_kernel<<<256, 256, 0, stream>>>(bufB, batch, sums, cnts, N);
    head_kernel<<<1, 256, 0, stream>>>(sums, cnts, lw1, lb1, lw2, lb2, lw3, lb3, out, G);
}

// Round 4
// 285.570 us; speedup vs baseline: 1.2984x; 1.2984x over previous
//
#include <hip/hip_runtime.h>
#include <hip/hip_bf16.h>

// GCN regressor: 3x GCNConv(64->64, normalize=False) + mean-pool + MLP(64->32->16->1)
// Round 2 kernel (resubmitted unchanged; two consecutive container failures):
//  - CSR record packed to 8B (int2{src, w-bits}): halves scattered-write line traffic.
//  - gemm fused into agg via linearity: agg(xW) == (agg x)W. Each layer = ONE kernel:
//    gather-accumulate raw features, epilogue applies W (LDS) + bias + relu.

#define HID 64

__global__ __launch_bounds__(256) void deg_kernel(const int* __restrict__ ei,
                                                  int* __restrict__ deg, int E) {
    int e = blockIdx.x * 256 + threadIdx.x;
    if (e < E) atomicAdd(&deg[ei[E + e]], 1);   // row 1 of edge_index = dst
}

__global__ __launch_bounds__(256) void scan1_kernel(const int* __restrict__ deg,
                                                    int* __restrict__ offs,
                                                    int* __restrict__ bsum, int N) {
    __shared__ int sh[256];
    int t = threadIdx.x;
    int i = blockIdx.x * 256 + t;
    int v = (i < N) ? deg[i] : 0;
    sh[t] = v;
    __syncthreads();
    #pragma unroll
    for (int d = 1; d < 256; d <<= 1) {
        int add = (t >= d) ? sh[t - d] : 0;
        __syncthreads();
        sh[t] += add;
        __syncthreads();
    }
    if (i < N) offs[i] = sh[t] - v;            // exclusive within block
    if (t == 255) bsum[blockIdx.x] = sh[255];  // block total
}

__global__ __launch_bounds__(256) void scan2_kernel(int* __restrict__ bsum, int nb) {
    __shared__ int sh[256];
    int t = threadIdx.x;
    int v = (t < nb) ? bsum[t] : 0;
    sh[t] = v;
    __syncthreads();
    #pragma unroll
    for (int d = 1; d < 256; d <<= 1) {
        int add = (t >= d) ? sh[t - d] : 0;
        __syncthreads();
        sh[t] += add;
        __syncthreads();
    }
    if (t < nb) bsum[t] = sh[t] - v;           // exclusive over blocks
}

__global__ __launch_bounds__(256) void scan3_kernel(int* __restrict__ offs,
                                                    const int* __restrict__ bsum,
                                                    int N, int E) {
    int i = blockIdx.x * 256 + threadIdx.x;
    if (i < N) offs[i] += bsum[blockIdx.x];
    if (i == 0) offs[N] = E;
}

__global__ __launch_bounds__(256) void copy_kernel(const int* __restrict__ a,
                                                   int* __restrict__ b, int n) {
    int i = blockIdx.x * 256 + threadIdx.x;
    if (i < n) b[i] = a[i];
}

// Packed 8B record per edge: {src, float_bits(w)} -> one scattered store, not two.
__global__ __launch_bounds__(256) void fill_kernel(const int* __restrict__ ei,
                                                   const float* __restrict__ ew,
                                                   int* __restrict__ cursor,
                                                   int2* __restrict__ csr, int E) {
    int e = blockIdx.x * 256 + threadIdx.x;
    if (e < E) {
        int d = ei[E + e];
        int slot = atomicAdd(&cursor[d], 1);
        csr[slot] = make_int2(ei[e], __float_as_int(ew[e]));
    }
}

// Fused layer: out[n][:] = relu( (sum_{e in CSR(n)} w_e * prev[src_e][:]) @ W + b )
// 16 lanes per node; lane l holds input channels 4l..4l+3 (float4) and computes
// output channels 4l..4l+3. Transform via width-16 shfl broadcasts + W in LDS.
__global__ __launch_bounds__(256) void agg_fused_kernel(const float* __restrict__ prev,
                                                        const int2* __restrict__ csr,
                                                        const int* __restrict__ offs,
                                                        const float* __restrict__ W,
                                                        const float* __restrict__ bias,
                                                        float* __restrict__ out, int N) {
    __shared__ float Wl[64 * 64];
    __shared__ float bl[64];
    for (int i = threadIdx.x; i < 64 * 64; i += 256) Wl[i] = W[i];
    if (threadIdx.x < 64) bl[threadIdx.x] = bias[threadIdx.x];
    __syncthreads();

    int g = (blockIdx.x * 256 + threadIdx.x) >> 4;   // node
    int l = threadIdx.x & 15;                        // lane in group
    if (g >= N) return;                              // no further __syncthreads below

    int e0 = offs[g], e1 = offs[g + 1];
    float4 acc = make_float4(0.f, 0.f, 0.f, 0.f);
    for (int e = e0; e < e1; ++e) {
        int2 rec = csr[e];
        float w = __int_as_float(rec.y);
        const float4 v = *reinterpret_cast<const float4*>(prev + (size_t)rec.x * 64 + l * 4);
        acc.x = fmaf(w, v.x, acc.x);
        acc.y = fmaf(w, v.y, acc.y);
        acc.z = fmaf(w, v.z, acc.z);
        acc.w = fmaf(w, v.w, acc.w);
    }

    // o[j] = sum_k acc_vec[k] * W[k][4l+j] + b[4l+j], j=0..3
    const float4 b4 = *reinterpret_cast<const float4*>(bl + l * 4);
    float4 o = b4;
    #pragma unroll
    for (int k2 = 0; k2 < 16; ++k2) {
        float c0 = __shfl(acc.x, k2, 16);   // channel 4*k2+0
        float c1 = __shfl(acc.y, k2, 16);   // channel 4*k2+1
        float c2 = __shfl(acc.z, k2, 16);   // channel 4*k2+2
        float c3 = __shfl(acc.w, k2, 16);   // channel 4*k2+3
        const float4 w0 = *reinterpret_cast<const float4*>(Wl + (4 * k2 + 0) * 64 + l * 4);
        const float4 w1 = *reinterpret_cast<const float4*>(Wl + (4 * k2 + 1) * 64 + l * 4);
        const float4 w2 = *reinterpret_cast<const float4*>(Wl + (4 * k2 + 2) * 64 + l * 4);
        const float4 w3 = *reinterpret_cast<const float4*>(Wl + (4 * k2 + 3) * 64 + l * 4);
        o.x = fmaf(c0, w0.x, o.x); o.y = fmaf(c0, w0.y, o.y);
        o.z = fmaf(c0, w0.z, o.z); o.w = fmaf(c0, w0.w, o.w);
        o.x = fmaf(c1, w1.x, o.x); o.y = fmaf(c1, w1.y, o.y);
        o.z = fmaf(c1, w1.z, o.z); o.w = fmaf(c1, w1.w, o.w);
        o.x = fmaf(c2, w2.x, o.x); o.y = fmaf(c2, w2.y, o.y);
        o.z = fmaf(c2, w2.z, o.z); o.w = fmaf(c2, w2.w, o.w);
        o.x = fmaf(c3, w3.x, o.x); o.y = fmaf(c3, w3.y, o.y);
        o.z = fmaf(c3, w3.z, o.z); o.w = fmaf(c3, w3.w, o.w);
    }
    float4 r;
    r.x = fmaxf(o.x, 0.f);
    r.y = fmaxf(o.y, 0.f);
    r.z = fmaxf(o.z, 0.f);
    r.w = fmaxf(o.w, 0.f);
    *reinterpret_cast<float4*>(out + (size_t)g * 64 + l * 4) = r;
}

// Mean-pool stage 1: sorted batch -> register run-length accumulate, atomic flush.
__global__ __launch_bounds__(256) void pool_kernel(const float* __restrict__ a,
                                                   const int* __restrict__ batch,
                                                   float* __restrict__ sums,
                                                   float* __restrict__ cnts, int N) {
    int c = threadIdx.x & 63;
    int sub = threadIdx.x >> 6;   // 0..3
    int chunk = (N + gridDim.x - 1) / gridDim.x;
    int start = blockIdx.x * chunk;
    int end = min(N, start + chunk);
    int curg = -1;
    float acc = 0.f, cacc = 0.f;
    for (int n = start + sub; n < end; n += 4) {
        int g = batch[n];
        if (g != curg) {
            if (curg >= 0) {
                atomicAdd(&sums[curg * 64 + c], acc);
                if (c == 0) atomicAdd(&cnts[curg], cacc);
            }
            curg = g; acc = 0.f; cacc = 0.f;
        }
        acc += a[(size_t)n * 64 + c];
        cacc += 1.f;
    }
    if (curg >= 0) {
        atomicAdd(&sums[curg * 64 + c], acc);
        if (c == 0) atomicAdd(&cnts[curg], cacc);
    }
}

// MLP head: pooled[G][64] -> relu(@lw1 64x32) -> relu(@lw2 32x16) -> @lw3 16x1
__global__ __launch_bounds__(256) void head_kernel(const float* __restrict__ sums,
                                                   const float* __restrict__ cnts,
                                                   const float* __restrict__ lw1,
                                                   const float* __restrict__ lb1,
                                                   const float* __restrict__ lw2,
                                                   const float* __restrict__ lb2,
                                                   const float* __restrict__ lw3,
                                                   const float* __restrict__ lb3,
                                                   float* __restrict__ out, int G) {
    __shared__ float pooled[64 * 64];
    __shared__ float z1[64 * 32];
    __shared__ float z2[64 * 16];
    int tid = threadIdx.x;
    for (int i = tid; i < G * 64; i += 256) {
        int g = i >> 6;
        float cn = cnts[g];
        cn = (cn < 1.f) ? 1.f : cn;
        pooled[i] = sums[i] / cn;
    }
    __syncthreads();
    for (int i = tid; i < G * 32; i += 256) {
        int g = i >> 5, j = i & 31;
        float acc = lb1[j];
        #pragma unroll
        for (int k = 0; k < 64; ++k) acc = fmaf(pooled[g * 64 + k], lw1[k * 32 + j], acc);
        z1[i] = fmaxf(acc, 0.f);
    }
    __syncthreads();
    for (int i = tid; i < G * 16; i += 256) {
        int g = i >> 4, j = i & 15;
        float acc = lb2[j];
        #pragma unroll
        for (int k = 0; k < 32; ++k) acc = fmaf(z1[g * 32 + k], lw2[k * 16 + j], acc);
        z2[i] = fmaxf(acc, 0.f);
    }
    __syncthreads();
    if (tid < G) {
        float acc = lb3[0];
        #pragma unroll
        for (int k = 0; k < 16; ++k) acc = fmaf(z2[tid * 16 + k], lw3[k], acc);
        out[tid] = acc;
    }
}

static inline size_t align256(size_t x) { return (x + 255) & ~(size_t)255; }

extern "C" void kernel_launch(void* const* d_in, const int* in_sizes, int n_in,
                              void* d_out, int out_size, void* d_ws, size_t ws_size,
                              hipStream_t stream) {
    const float* x     = (const float*)d_in[0];
    const int*   ei    = (const int*)d_in[1];     // (2,E): [0..E)=src, [E..2E)=dst
    const float* ew    = (const float*)d_in[2];
    const int*   batch = (const int*)d_in[3];
    const float* W1 = (const float*)d_in[4];
    const float* b1 = (const float*)d_in[5];
    const float* W2 = (const float*)d_in[6];
    const float* b2 = (const float*)d_in[7];
    const float* W3 = (const float*)d_in[8];
    const float* b3 = (const float*)d_in[9];
    const float* lw1 = (const float*)d_in[10];
    const float* lb1 = (const float*)d_in[11];
    const float* lw2 = (const float*)d_in[12];
    const float* lb2 = (const float*)d_in[13];
    const float* lw3 = (const float*)d_in[14];
    const float* lb3 = (const float*)d_in[15];
    float* out = (float*)d_out;

    const int N = in_sizes[0] / 64;
    const int E = in_sizes[2];
    const int G = out_size;

    // Workspace carve
    char* w = (char*)d_ws;
    size_t off = 0;
    auto carve = [&](size_t bytes) -> void* {
        void* p = w + off;
        off = align256(off + bytes);
        return p;
    };
    float* bufA   = (float*)carve((size_t)N * 64 * 4);
    float* bufB   = (float*)carve((size_t)N * 64 * 4);
    int2*  csr    = (int2*)carve((size_t)E * 8);
    int*   deg    = (int*)carve((size_t)N * 4);
    int*   offs   = (int*)carve((size_t)(N + 1) * 4);
    int*   cursor = (int*)carve((size_t)N * 4);
    int*   bsum   = (int*)carve(256 * 4);
    float* sums   = (float*)carve((size_t)G * 64 * 4);
    float* cnts   = (float*)carve((size_t)G * 4);
    (void)ws_size; (void)n_in;

    const int EB = (E + 255) / 256;        // edge blocks
    const int NB = (N + 255) / 256;        // node blocks (<=256 for scan2)

    // ---- CSR build (once; dst reused for all 3 layers) ----
    hipMemsetAsync(deg, 0, (size_t)N * 4, stream);
    hipMemsetAsync(sums, 0, (size_t)G * 64 * 4, stream);
    hipMemsetAsync(cnts, 0, (size_t)G * 4, stream);
    deg_kernel<<<EB, 256, 0, stream>>>(ei, deg, E);
    scan1_kernel<<<NB, 256, 0, stream>>>(deg, offs, bsum, N);
    scan2_kernel<<<1, 256, 0, stream>>>(bsum, NB);
    scan3_kernel<<<NB, 256, 0, stream>>>(offs, bsum, N, E);
    copy_kernel<<<NB, 256, 0, stream>>>(offs, cursor, N);
    fill_kernel<<<EB, 256, 0, stream>>>(ei, ew, cursor, csr, E);

    const int AGG_BLOCKS = (N * 16 + 255) / 256;

    // ---- 3 fused layers: agg (raw features) -> @W + b -> relu ----
    agg_fused_kernel<<<AGG_BLOCKS, 256, 0, stream>>>(x,    csr, offs, W1, b1, bufA, N);
    agg_fused_kernel<<<AGG_BLOCKS, 256, 0, stream>>>(bufA, csr, offs, W2, b2, bufB, N);
    agg_fused_kernel<<<AGG_BLOCKS, 256, 0, stream>>>(bufB, csr, offs, W3, b3, bufA, N);

    // ---- pool + head ----
    pool_kernel<<<1024, 256, 0, stream>>>(bufA, batch, sums, cnts, N);
    head_kernel<<<1, 256, 0, stream>>>(sums, cnts, lw1, lb1, lw2, lb2, lw3, lb3, out, G);
}

// Round 5
// 262.709 us; speedup vs baseline: 1.4114x; 1.0870x over previous
//
#include <hip/hip_runtime.h>
#include <hip/hip_bf16.h>

// GCN regressor: 3x GCNConv(64->64, normalize=False) + mean-pool + MLP(64->32->16->1)
// Round 5:
//  - agg_fused edge loop unrolled x4: 4 independent row gathers in flight per
//    16-lane group (was a serial load->gather->fma chain). Same summation order.
//  - copy_kernel folded into scan3 (cursor init written there).
//  - fill/deg/pool/head unchanged for attribution.

#define HID 64

__global__ __launch_bounds__(256) void deg_kernel(const int* __restrict__ ei,
                                                  int* __restrict__ deg, int E) {
    int e = blockIdx.x * 256 + threadIdx.x;
    if (e < E) atomicAdd(&deg[ei[E + e]], 1);   // row 1 of edge_index = dst
}

__global__ __launch_bounds__(256) void scan1_kernel(const int* __restrict__ deg,
                                                    int* __restrict__ offs,
                                                    int* __restrict__ bsum, int N) {
    __shared__ int sh[256];
    int t = threadIdx.x;
    int i = blockIdx.x * 256 + t;
    int v = (i < N) ? deg[i] : 0;
    sh[t] = v;
    __syncthreads();
    #pragma unroll
    for (int d = 1; d < 256; d <<= 1) {
        int add = (t >= d) ? sh[t - d] : 0;
        __syncthreads();
        sh[t] += add;
        __syncthreads();
    }
    if (i < N) offs[i] = sh[t] - v;            // exclusive within block
    if (t == 255) bsum[blockIdx.x] = sh[255];  // block total
}

__global__ __launch_bounds__(256) void scan2_kernel(int* __restrict__ bsum, int nb) {
    __shared__ int sh[256];
    int t = threadIdx.x;
    int v = (t < nb) ? bsum[t] : 0;
    sh[t] = v;
    __syncthreads();
    #pragma unroll
    for (int d = 1; d < 256; d <<= 1) {
        int add = (t >= d) ? sh[t - d] : 0;
        __syncthreads();
        sh[t] += add;
        __syncthreads();
    }
    if (t < nb) bsum[t] = sh[t] - v;           // exclusive over blocks
}

// Also initializes cursor = offs (replaces copy_kernel).
__global__ __launch_bounds__(256) void scan3_kernel(int* __restrict__ offs,
                                                    const int* __restrict__ bsum,
                                                    int* __restrict__ cursor,
                                                    int N, int E) {
    int i = blockIdx.x * 256 + threadIdx.x;
    if (i < N) {
        int v = offs[i] + bsum[blockIdx.x];
        offs[i] = v;
        cursor[i] = v;
    }
    if (i == 0) offs[N] = E;
}

// Packed 8B record per edge: {src, float_bits(w)} -> one scattered store, not two.
__global__ __launch_bounds__(256) void fill_kernel(const int* __restrict__ ei,
                                                   const float* __restrict__ ew,
                                                   int* __restrict__ cursor,
                                                   int2* __restrict__ csr, int E) {
    int e = blockIdx.x * 256 + threadIdx.x;
    if (e < E) {
        int d = ei[E + e];
        int slot = atomicAdd(&cursor[d], 1);
        csr[slot] = make_int2(ei[e], __float_as_int(ew[e]));
    }
}

// Fused layer: out[n][:] = relu( (sum_{e in CSR(n)} w_e * prev[src_e][:]) @ W + b )
// 16 lanes per node; lane l holds input channels 4l..4l+3 (float4) and computes
// output channels 4l..4l+3. Edge loop unrolled x4 for memory-level parallelism.
__global__ __launch_bounds__(256) void agg_fused_kernel(const float* __restrict__ prev,
                                                        const int2* __restrict__ csr,
                                                        const int* __restrict__ offs,
                                                        const float* __restrict__ W,
                                                        const float* __restrict__ bias,
                                                        float* __restrict__ out, int N) {
    __shared__ float Wl[64 * 64];
    __shared__ float bl[64];
    for (int i = threadIdx.x; i < 64 * 64; i += 256) Wl[i] = W[i];
    if (threadIdx.x < 64) bl[threadIdx.x] = bias[threadIdx.x];
    __syncthreads();

    int g = (blockIdx.x * 256 + threadIdx.x) >> 4;   // node
    int l = threadIdx.x & 15;                        // lane in group
    if (g >= N) return;                              // no further __syncthreads below

    int e0 = offs[g], e1 = offs[g + 1];
    float4 acc = make_float4(0.f, 0.f, 0.f, 0.f);
    int e = e0;
    for (; e + 4 <= e1; e += 4) {
        // 4 independent records -> 4 independent row gathers in flight.
        int2 r0 = csr[e + 0];
        int2 r1 = csr[e + 1];
        int2 r2 = csr[e + 2];
        int2 r3 = csr[e + 3];
        const float4 v0 = *reinterpret_cast<const float4*>(prev + (size_t)r0.x * 64 + l * 4);
        const float4 v1 = *reinterpret_cast<const float4*>(prev + (size_t)r1.x * 64 + l * 4);
        const float4 v2 = *reinterpret_cast<const float4*>(prev + (size_t)r2.x * 64 + l * 4);
        const float4 v3 = *reinterpret_cast<const float4*>(prev + (size_t)r3.x * 64 + l * 4);
        const float w0 = __int_as_float(r0.y);
        const float w1 = __int_as_float(r1.y);
        const float w2 = __int_as_float(r2.y);
        const float w3 = __int_as_float(r3.y);
        // accumulate in original edge order (bitwise-stable vs unrolled=1)
        acc.x = fmaf(w0, v0.x, acc.x); acc.y = fmaf(w0, v0.y, acc.y);
        acc.z = fmaf(w0, v0.z, acc.z); acc.w = fmaf(w0, v0.w, acc.w);
        acc.x = fmaf(w1, v1.x, acc.x); acc.y = fmaf(w1, v1.y, acc.y);
        acc.z = fmaf(w1, v1.z, acc.z); acc.w = fmaf(w1, v1.w, acc.w);
        acc.x = fmaf(w2, v2.x, acc.x); acc.y = fmaf(w2, v2.y, acc.y);
        acc.z = fmaf(w2, v2.z, acc.z); acc.w = fmaf(w2, v2.w, acc.w);
        acc.x = fmaf(w3, v3.x, acc.x); acc.y = fmaf(w3, v3.y, acc.y);
        acc.z = fmaf(w3, v3.z, acc.z); acc.w = fmaf(w3, v3.w, acc.w);
    }
    for (; e < e1; ++e) {
        int2 rec = csr[e];
        float w = __int_as_float(rec.y);
        const float4 v = *reinterpret_cast<const float4*>(prev + (size_t)rec.x * 64 + l * 4);
        acc.x = fmaf(w, v.x, acc.x);
        acc.y = fmaf(w, v.y, acc.y);
        acc.z = fmaf(w, v.z, acc.z);
        acc.w = fmaf(w, v.w, acc.w);
    }

    // o[j] = sum_k acc_vec[k] * W[k][4l+j] + b[4l+j], j=0..3
    const float4 b4 = *reinterpret_cast<const float4*>(bl + l * 4);
    float4 o = b4;
    #pragma unroll
    for (int k2 = 0; k2 < 16; ++k2) {
        float c0 = __shfl(acc.x, k2, 16);   // channel 4*k2+0
        float c1 = __shfl(acc.y, k2, 16);   // channel 4*k2+1
        float c2 = __shfl(acc.z, k2, 16);   // channel 4*k2+2
        float c3 = __shfl(acc.w, k2, 16);   // channel 4*k2+3
        const float4 w0 = *reinterpret_cast<const float4*>(Wl + (4 * k2 + 0) * 64 + l * 4);
        const float4 w1 = *reinterpret_cast<const float4*>(Wl + (4 * k2 + 1) * 64 + l * 4);
        const float4 w2 = *reinterpret_cast<const float4*>(Wl + (4 * k2 + 2) * 64 + l * 4);
        const float4 w3 = *reinterpret_cast<const float4*>(Wl + (4 * k2 + 3) * 64 + l * 4);
        o.x = fmaf(c0, w0.x, o.x); o.y = fmaf(c0, w0.y, o.y);
        o.z = fmaf(c0, w0.z, o.z); o.w = fmaf(c0, w0.w, o.w);
        o.x = fmaf(c1, w1.x, o.x); o.y = fmaf(c1, w1.y, o.y);
        o.z = fmaf(c1, w1.z, o.z); o.w = fmaf(c1, w1.w, o.w);
        o.x = fmaf(c2, w2.x, o.x); o.y = fmaf(c2, w2.y, o.y);
        o.z = fmaf(c2, w2.z, o.z); o.w = fmaf(c2, w2.w, o.w);
        o.x = fmaf(c3, w3.x, o.x); o.y = fmaf(c3, w3.y, o.y);
        o.z = fmaf(c3, w3.z, o.z); o.w = fmaf(c3, w3.w, o.w);
    }
    float4 r;
    r.x = fmaxf(o.x, 0.f);
    r.y = fmaxf(o.y, 0.f);
    r.z = fmaxf(o.z, 0.f);
    r.w = fmaxf(o.w, 0.f);
    *reinterpret_cast<float4*>(out + (size_t)g * 64 + l * 4) = r;
}

// Mean-pool stage 1: sorted batch -> register run-length accumulate, atomic flush.
__global__ __launch_bounds__(256) void pool_kernel(const float* __restrict__ a,
                                                   const int* __restrict__ batch,
                                                   float* __restrict__ sums,
                                                   float* __restrict__ cnts, int N) {
    int c = threadIdx.x & 63;
    int sub = threadIdx.x >> 6;   // 0..3
    int chunk = (N + gridDim.x - 1) / gridDim.x;
    int start = blockIdx.x * chunk;
    int end = min(N, start + chunk);
    int curg = -1;
    float acc = 0.f, cacc = 0.f;
    for (int n = start + sub; n < end; n += 4) {
        int g = batch[n];
        if (g != curg) {
            if (curg >= 0) {
                atomicAdd(&sums[curg * 64 + c], acc);
                if (c == 0) atomicAdd(&cnts[curg], cacc);
            }
            curg = g; acc = 0.f; cacc = 0.f;
        }
        acc += a[(size_t)n * 64 + c];
        cacc += 1.f;
    }
    if (curg >= 0) {
        atomicAdd(&sums[curg * 64 + c], acc);
        if (c == 0) atomicAdd(&cnts[curg], cacc);
    }
}

// MLP head: pooled[G][64] -> relu(@lw1 64x32) -> relu(@lw2 32x16) -> @lw3 16x1
__global__ __launch_bounds__(256) void head_kernel(const float* __restrict__ sums,
                                                   const float* __restrict__ cnts,
                                                   const float* __restrict__ lw1,
                                                   const float* __restrict__ lb1,
                                                   const float* __restrict__ lw2,
                                                   const float* __restrict__ lb2,
                                                   const float* __restrict__ lw3,
                                                   const float* __restrict__ lb3,
                                                   float* __restrict__ out, int G) {
    __shared__ float pooled[64 * 64];
    __shared__ float z1[64 * 32];
    __shared__ float z2[64 * 16];
    int tid = threadIdx.x;
    for (int i = tid; i < G * 64; i += 256) {
        int g = i >> 6;
        float cn = cnts[g];
        cn = (cn < 1.f) ? 1.f : cn;
        pooled[i] = sums[i] / cn;
    }
    __syncthreads();
    for (int i = tid; i < G * 32; i += 256) {
        int g = i >> 5, j = i & 31;
        float acc = lb1[j];
        #pragma unroll
        for (int k = 0; k < 64; ++k) acc = fmaf(pooled[g * 64 + k], lw1[k * 32 + j], acc);
        z1[i] = fmaxf(acc, 0.f);
    }
    __syncthreads();
    for (int i = tid; i < G * 16; i += 256) {
        int g = i >> 4, j = i & 15;
        float acc = lb2[j];
        #pragma unroll
        for (int k = 0; k < 32; ++k) acc = fmaf(z1[g * 32 + k], lw2[k * 16 + j], acc);
        z2[i] = fmaxf(acc, 0.f);
    }
    __syncthreads();
    if (tid < G) {
        float acc = lb3[0];
        #pragma unroll
        for (int k = 0; k < 16; ++k) acc = fmaf(z2[tid * 16 + k], lw3[k], acc);
        out[tid] = acc;
    }
}

static inline size_t align256(size_t x) { return (x + 255) & ~(size_t)255; }

extern "C" void kernel_launch(void* const* d_in, const int* in_sizes, int n_in,
                              void* d_out, int out_size, void* d_ws, size_t ws_size,
                              hipStream_t stream) {
    const float* x     = (const float*)d_in[0];
    const int*   ei    = (const int*)d_in[1];     // (2,E): [0..E)=src, [E..2E)=dst
    const float* ew    = (const float*)d_in[2];
    const int*   batch = (const int*)d_in[3];
    const float* W1 = (const float*)d_in[4];
    const float* b1 = (const float*)d_in[5];
    const float* W2 = (const float*)d_in[6];
    const float* b2 = (const float*)d_in[7];
    const float* W3 = (const float*)d_in[8];
    const float* b3 = (const float*)d_in[9];
    const float* lw1 = (const float*)d_in[10];
    const float* lb1 = (const float*)d_in[11];
    const float* lw2 = (const float*)d_in[12];
    const float* lb2 = (const float*)d_in[13];
    const float* lw3 = (const float*)d_in[14];
    const float* lb3 = (const float*)d_in[15];
    float* out = (float*)d_out;

    const int N = in_sizes[0] / 64;
    const int E = in_sizes[2];
    const int G = out_size;

    // Workspace carve
    char* w = (char*)d_ws;
    size_t off = 0;
    auto carve = [&](size_t bytes) -> void* {
        void* p = w + off;
        off = align256(off + bytes);
        return p;
    };
    float* bufA   = (float*)carve((size_t)N * 64 * 4);
    float* bufB   = (float*)carve((size_t)N * 64 * 4);
    int2*  csr    = (int2*)carve((size_t)E * 8);
    int*   deg    = (int*)carve((size_t)N * 4);
    int*   offs   = (int*)carve((size_t)(N + 1) * 4);
    int*   cursor = (int*)carve((size_t)N * 4);
    int*   bsum   = (int*)carve(256 * 4);
    float* sums   = (float*)carve((size_t)G * 64 * 4);
    float* cnts   = (float*)carve((size_t)G * 4);
    (void)ws_size; (void)n_in;

    const int EB = (E + 255) / 256;        // edge blocks
    const int NB = (N + 255) / 256;        // node blocks (<=256 for scan2)

    // ---- CSR build (once; dst reused for all 3 layers) ----
    hipMemsetAsync(deg, 0, (size_t)N * 4, stream);
    hipMemsetAsync(sums, 0, (size_t)G * 64 * 4, stream);
    hipMemsetAsync(cnts, 0, (size_t)G * 4, stream);
    deg_kernel<<<EB, 256, 0, stream>>>(ei, deg, E);
    scan1_kernel<<<NB, 256, 0, stream>>>(deg, offs, bsum, N);
    scan2_kernel<<<1, 256, 0, stream>>>(bsum, NB);
    scan3_kernel<<<NB, 256, 0, stream>>>(offs, bsum, cursor, N, E);
    fill_kernel<<<EB, 256, 0, stream>>>(ei, ew, cursor, csr, E);

    const int AGG_BLOCKS = (N * 16 + 255) / 256;

    // ---- 3 fused layers: agg (raw features) -> @W + b -> relu ----
    agg_fused_kernel<<<AGG_BLOCKS, 256, 0, stream>>>(x,    csr, offs, W1, b1, bufA, N);
    agg_fused_kernel<<<AGG_BLOCKS, 256, 0, stream>>>(bufA, csr, offs, W2, b2, bufB, N);
    agg_fused_kernel<<<AGG_BLOCKS, 256, 0, stream>>>(bufB, csr, offs, W3, b3, bufA, N);

    // ---- pool + head ----
    pool_kernel<<<1024, 256, 0, stream>>>(bufA, batch, sums, cnts, N);
    head_kernel<<<1, 256, 0, stream>>>(sums, cnts, lw1, lb1, lw2, lb2, lw3, lb3, out, G);
}

// Round 6
// 206.152 us; speedup vs baseline: 1.7986x; 1.2743x over previous
//
#include <hip/hip_runtime.h>
#include <hip/hip_bf16.h>

// GCN regressor: 3x GCNConv(64->64, normalize=False) + mean-pool + MLP(64->32->16->1)
// Round 6: CSR build reworked as bucketed counting sort (all writes dense):
//   histA (per-block x per-bucket LDS histogram) -> scanB1/scanB2 (slice offsets)
//   -> passB (edges into bucket-partitioned ebuf; per-block slices contiguous)
//   -> passC (per-bucket counting sort -> final CSR + offs).
// Replaces deg/scan1/scan2/scan3/fill (scattered 8B stores = 52MB line traffic;
// scattered global atomics). ebuf aliases bufA (dead before agg layer 1).
// agg/pool/head unchanged for attribution.

#define HID 64
#define KNBLK 256   // partition blocks for hist/scatter passes (must be 256: scanB1 scans 256)

// ---- pass A: per-block, per-bucket histogram. bucket = dst >> 8 ----
__global__ __launch_bounds__(256) void histA_kernel(const int* __restrict__ ei,
                                                    int* __restrict__ counts,
                                                    int E, int K, int chunk) {
    __shared__ int hist[256];
    int t = threadIdx.x, b = blockIdx.x;
    hist[t] = 0;
    __syncthreads();
    int s = b * chunk, e1 = min(E, s + chunk);
    for (int i = s + t; i < e1; i += 256)
        atomicAdd(&hist[ei[E + i] >> 8], 1);
    __syncthreads();
    if (t < K) counts[b * K + t] = hist[t];
}

// ---- scan B1: per bucket k, exclusive scan of counts[blk][k] over blk=0..255.
//      In-place: counts[blk*K+k] becomes the within-bucket block offset. ----
__global__ __launch_bounds__(256) void scanB1_kernel(int* __restrict__ counts,
                                                     int* __restrict__ btot, int K) {
    __shared__ int sh[256];
    int k = blockIdx.x, t = threadIdx.x;
    int v = counts[t * K + k];
    sh[t] = v;
    __syncthreads();
    #pragma unroll
    for (int d = 1; d < 256; d <<= 1) {
        int add = (t >= d) ? sh[t - d] : 0;
        __syncthreads();
        sh[t] += add;
        __syncthreads();
    }
    counts[t * K + k] = sh[t] - v;          // exclusive over blocks
    if (t == 255) btot[k] = sh[255];        // bucket total
}

// ---- scan B2: exclusive scan of bucket totals -> bucket base offsets bb0[0..K] ----
__global__ __launch_bounds__(256) void scanB2_kernel(const int* __restrict__ btot,
                                                     int* __restrict__ bb0, int K) {
    __shared__ int sh[256];
    int t = threadIdx.x;
    int v = (t < K) ? btot[t] : 0;
    sh[t] = v;
    __syncthreads();
    #pragma unroll
    for (int d = 1; d < 256; d <<= 1) {
        int add = (t >= d) ? sh[t - d] : 0;
        __syncthreads();
        sh[t] += add;
        __syncthreads();
    }
    if (t < K) bb0[t] = sh[t] - v;
    if (t == 255) bb0[K] = sh[255];         // == E
}

// ---- pass B: scatter edges to bucket-partitioned ebuf. Each (block,bucket)
//      slice is contiguous -> dense line writes. ----
__global__ __launch_bounds__(256) void passB_kernel(const int* __restrict__ ei,
                                                    const float* __restrict__ ew,
                                                    const int* __restrict__ counts,
                                                    const int* __restrict__ bb0,
                                                    int4* __restrict__ ebuf,
                                                    int E, int K, int chunk) {
    __shared__ int lcur[256];
    int t = threadIdx.x, b = blockIdx.x;
    lcur[t] = 0;
    __syncthreads();
    int s = b * chunk, e1 = min(E, s + chunk);
    for (int i = s + t; i < e1; i += 256) {
        int src = ei[i];
        int dst = ei[E + i];
        float w = ew[i];
        int k = dst >> 8;
        int idx = atomicAdd(&lcur[k], 1);
        int slot = bb0[k] + counts[b * K + k] + idx;
        ebuf[slot] = make_int4(src, __float_as_int(w), dst, 0);
    }
}

// ---- pass C: per-bucket counting sort -> final CSR (int2{src,wbits}) + offs ----
__global__ __launch_bounds__(256) void passC_kernel(const int4* __restrict__ ebuf,
                                                    const int* __restrict__ bb0,
                                                    int2* __restrict__ csr,
                                                    int* __restrict__ offs,
                                                    int N, int E, int K) {
    __shared__ int ldeg[256];
    __shared__ int sh[256];
    __shared__ int lofs[256];
    int b = blockIdx.x, t = threadIdx.x;
    int gb0 = bb0[b], gb1 = bb0[b + 1];
    int cnt = gb1 - gb0;
    int base = b << 8;
    ldeg[t] = 0;
    __syncthreads();
    for (int i = t; i < cnt; i += 256)
        atomicAdd(&ldeg[ebuf[gb0 + i].z & 255], 1);
    __syncthreads();
    int v = ldeg[t];
    sh[t] = v;
    __syncthreads();
    #pragma unroll
    for (int d = 1; d < 256; d <<= 1) {
        int add = (t >= d) ? sh[t - d] : 0;
        __syncthreads();
        sh[t] += add;
        __syncthreads();
    }
    lofs[t] = sh[t] - v;                      // exclusive local offset (also cursor below)
    int nInB = min(256, N - base);
    if (t < nInB) offs[base + t] = gb0 + lofs[t];
    if (b == K - 1 && t == 0) offs[N] = E;
    __syncthreads();
    for (int i = t; i < cnt; i += 256) {
        int4 r = ebuf[gb0 + i];
        int d = r.z & 255;
        int pos = atomicAdd(&lofs[d], 1);     // reuse lofs as cursor
        csr[gb0 + pos] = make_int2(r.x, r.y); // writes confined to this bucket's region
    }
}

// Fused layer: out[n][:] = relu( (sum_{e in CSR(n)} w_e * prev[src_e][:]) @ W + b )
// 16 lanes per node; lane l holds input channels 4l..4l+3 (float4) and computes
// output channels 4l..4l+3. Edge loop unrolled x4 for memory-level parallelism.
__global__ __launch_bounds__(256) void agg_fused_kernel(const float* __restrict__ prev,
                                                        const int2* __restrict__ csr,
                                                        const int* __restrict__ offs,
                                                        const float* __restrict__ W,
                                                        const float* __restrict__ bias,
                                                        float* __restrict__ out, int N) {
    __shared__ float Wl[64 * 64];
    __shared__ float bl[64];
    for (int i = threadIdx.x; i < 64 * 64; i += 256) Wl[i] = W[i];
    if (threadIdx.x < 64) bl[threadIdx.x] = bias[threadIdx.x];
    __syncthreads();

    int g = (blockIdx.x * 256 + threadIdx.x) >> 4;   // node
    int l = threadIdx.x & 15;                        // lane in group
    if (g >= N) return;                              // no further __syncthreads below

    int e0 = offs[g], e1 = offs[g + 1];
    float4 acc = make_float4(0.f, 0.f, 0.f, 0.f);
    int e = e0;
    for (; e + 4 <= e1; e += 4) {
        int2 r0 = csr[e + 0];
        int2 r1 = csr[e + 1];
        int2 r2 = csr[e + 2];
        int2 r3 = csr[e + 3];
        const float4 v0 = *reinterpret_cast<const float4*>(prev + (size_t)r0.x * 64 + l * 4);
        const float4 v1 = *reinterpret_cast<const float4*>(prev + (size_t)r1.x * 64 + l * 4);
        const float4 v2 = *reinterpret_cast<const float4*>(prev + (size_t)r2.x * 64 + l * 4);
        const float4 v3 = *reinterpret_cast<const float4*>(prev + (size_t)r3.x * 64 + l * 4);
        const float w0 = __int_as_float(r0.y);
        const float w1 = __int_as_float(r1.y);
        const float w2 = __int_as_float(r2.y);
        const float w3 = __int_as_float(r3.y);
        acc.x = fmaf(w0, v0.x, acc.x); acc.y = fmaf(w0, v0.y, acc.y);
        acc.z = fmaf(w0, v0.z, acc.z); acc.w = fmaf(w0, v0.w, acc.w);
        acc.x = fmaf(w1, v1.x, acc.x); acc.y = fmaf(w1, v1.y, acc.y);
        acc.z = fmaf(w1, v1.z, acc.z); acc.w = fmaf(w1, v1.w, acc.w);
        acc.x = fmaf(w2, v2.x, acc.x); acc.y = fmaf(w2, v2.y, acc.y);
        acc.z = fmaf(w2, v2.z, acc.z); acc.w = fmaf(w2, v2.w, acc.w);
        acc.x = fmaf(w3, v3.x, acc.x); acc.y = fmaf(w3, v3.y, acc.y);
        acc.z = fmaf(w3, v3.z, acc.z); acc.w = fmaf(w3, v3.w, acc.w);
    }
    for (; e < e1; ++e) {
        int2 rec = csr[e];
        float w = __int_as_float(rec.y);
        const float4 v = *reinterpret_cast<const float4*>(prev + (size_t)rec.x * 64 + l * 4);
        acc.x = fmaf(w, v.x, acc.x);
        acc.y = fmaf(w, v.y, acc.y);
        acc.z = fmaf(w, v.z, acc.z);
        acc.w = fmaf(w, v.w, acc.w);
    }

    const float4 b4 = *reinterpret_cast<const float4*>(bl + l * 4);
    float4 o = b4;
    #pragma unroll
    for (int k2 = 0; k2 < 16; ++k2) {
        float c0 = __shfl(acc.x, k2, 16);
        float c1 = __shfl(acc.y, k2, 16);
        float c2 = __shfl(acc.z, k2, 16);
        float c3 = __shfl(acc.w, k2, 16);
        const float4 w0 = *reinterpret_cast<const float4*>(Wl + (4 * k2 + 0) * 64 + l * 4);
        const float4 w1 = *reinterpret_cast<const float4*>(Wl + (4 * k2 + 1) * 64 + l * 4);
        const float4 w2 = *reinterpret_cast<const float4*>(Wl + (4 * k2 + 2) * 64 + l * 4);
        const float4 w3 = *reinterpret_cast<const float4*>(Wl + (4 * k2 + 3) * 64 + l * 4);
        o.x = fmaf(c0, w0.x, o.x); o.y = fmaf(c0, w0.y, o.y);
        o.z = fmaf(c0, w0.z, o.z); o.w = fmaf(c0, w0.w, o.w);
        o.x = fmaf(c1, w1.x, o.x); o.y = fmaf(c1, w1.y, o.y);
        o.z = fmaf(c1, w1.z, o.z); o.w = fmaf(c1, w1.w, o.w);
        o.x = fmaf(c2, w2.x, o.x); o.y = fmaf(c2, w2.y, o.y);
        o.z = fmaf(c2, w2.z, o.z); o.w = fmaf(c2, w2.w, o.w);
        o.x = fmaf(c3, w3.x, o.x); o.y = fmaf(c3, w3.y, o.y);
        o.z = fmaf(c3, w3.z, o.z); o.w = fmaf(c3, w3.w, o.w);
    }
    float4 r;
    r.x = fmaxf(o.x, 0.f);
    r.y = fmaxf(o.y, 0.f);
    r.z = fmaxf(o.z, 0.f);
    r.w = fmaxf(o.w, 0.f);
    *reinterpret_cast<float4*>(out + (size_t)g * 64 + l * 4) = r;
}

// Mean-pool stage 1: sorted batch -> register run-length accumulate, atomic flush.
__global__ __launch_bounds__(256) void pool_kernel(const float* __restrict__ a,
                                                   const int* __restrict__ batch,
                                                   float* __restrict__ sums,
                                                   float* __restrict__ cnts, int N) {
    int c = threadIdx.x & 63;
    int sub = threadIdx.x >> 6;   // 0..3
    int chunk = (N + gridDim.x - 1) / gridDim.x;
    int start = blockIdx.x * chunk;
    int end = min(N, start + chunk);
    int curg = -1;
    float acc = 0.f, cacc = 0.f;
    for (int n = start + sub; n < end; n += 4) {
        int g = batch[n];
        if (g != curg) {
            if (curg >= 0) {
                atomicAdd(&sums[curg * 64 + c], acc);
                if (c == 0) atomicAdd(&cnts[curg], cacc);
            }
            curg = g; acc = 0.f; cacc = 0.f;
        }
        acc += a[(size_t)n * 64 + c];
        cacc += 1.f;
    }
    if (curg >= 0) {
        atomicAdd(&sums[curg * 64 + c], acc);
        if (c == 0) atomicAdd(&cnts[curg], cacc);
    }
}

// MLP head: pooled[G][64] -> relu(@lw1 64x32) -> relu(@lw2 32x16) -> @lw3 16x1
__global__ __launch_bounds__(256) void head_kernel(const float* __restrict__ sums,
                                                   const float* __restrict__ cnts,
                                                   const float* __restrict__ lw1,
                                                   const float* __restrict__ lb1,
                                                   const float* __restrict__ lw2,
                                                   const float* __restrict__ lb2,
                                                   const float* __restrict__ lw3,
                                                   const float* __restrict__ lb3,
                                                   float* __restrict__ out, int G) {
    __shared__ float pooled[64 * 64];
    __shared__ float z1[64 * 32];
    __shared__ float z2[64 * 16];
    int tid = threadIdx.x;
    for (int i = tid; i < G * 64; i += 256) {
        int g = i >> 6;
        float cn = cnts[g];
        cn = (cn < 1.f) ? 1.f : cn;
        pooled[i] = sums[i] / cn;
    }
    __syncthreads();
    for (int i = tid; i < G * 32; i += 256) {
        int g = i >> 5, j = i & 31;
        float acc = lb1[j];
        #pragma unroll
        for (int k = 0; k < 64; ++k) acc = fmaf(pooled[g * 64 + k], lw1[k * 32 + j], acc);
        z1[i] = fmaxf(acc, 0.f);
    }
    __syncthreads();
    for (int i = tid; i < G * 16; i += 256) {
        int g = i >> 4, j = i & 15;
        float acc = lb2[j];
        #pragma unroll
        for (int k = 0; k < 32; ++k) acc = fmaf(z1[g * 32 + k], lw2[k * 16 + j], acc);
        z2[i] = fmaxf(acc, 0.f);
    }
    __syncthreads();
    if (tid < G) {
        float acc = lb3[0];
        #pragma unroll
        for (int k = 0; k < 16; ++k) acc = fmaf(z2[tid * 16 + k], lw3[k], acc);
        out[tid] = acc;
    }
}

static inline size_t align256(size_t x) { return (x + 255) & ~(size_t)255; }

extern "C" void kernel_launch(void* const* d_in, const int* in_sizes, int n_in,
                              void* d_out, int out_size, void* d_ws, size_t ws_size,
                              hipStream_t stream) {
    const float* x     = (const float*)d_in[0];
    const int*   ei    = (const int*)d_in[1];     // (2,E): [0..E)=src, [E..2E)=dst
    const float* ew    = (const float*)d_in[2];
    const int*   batch = (const int*)d_in[3];
    const float* W1 = (const float*)d_in[4];
    const float* b1 = (const float*)d_in[5];
    const float* W2 = (const float*)d_in[6];
    const float* b2 = (const float*)d_in[7];
    const float* W3 = (const float*)d_in[8];
    const float* b3 = (const float*)d_in[9];
    const float* lw1 = (const float*)d_in[10];
    const float* lb1 = (const float*)d_in[11];
    const float* lw2 = (const float*)d_in[12];
    const float* lb2 = (const float*)d_in[13];
    const float* lw3 = (const float*)d_in[14];
    const float* lb3 = (const float*)d_in[15];
    float* out = (float*)d_out;

    const int N = in_sizes[0] / 64;
    const int E = in_sizes[2];
    const int G = out_size;
    const int K = (N + 255) >> 8;          // buckets of 256 nodes
    const int chunk = (E + KNBLK - 1) / KNBLK;

    // Workspace carve
    char* w = (char*)d_ws;
    size_t off = 0;
    auto carve = [&](size_t bytes) -> void* {
        void* p = w + off;
        off = align256(off + bytes);
        return p;
    };
    float* bufA   = (float*)carve((size_t)N * 64 * 4);   // also aliases ebuf (dead before agg1)
    float* bufB   = (float*)carve((size_t)N * 64 * 4);
    int2*  csr    = (int2*)carve((size_t)E * 8);
    int*   counts = (int*)carve((size_t)KNBLK * K * 4);
    int*   btot   = (int*)carve((size_t)K * 4);
    int*   bb0    = (int*)carve((size_t)(K + 1) * 4);
    int*   offs   = (int*)carve((size_t)(N + 1) * 4);
    float* sums   = (float*)carve((size_t)G * 64 * 4);
    float* cnts   = (float*)carve((size_t)G * 4);
    int4*  ebuf   = (int4*)bufA;                         // E*16B == N*64*4B when E=16N/... fits: 800K*16=12.8MB
    (void)ws_size; (void)n_in;

    hipMemsetAsync(sums, 0, (size_t)G * 64 * 4, stream);
    hipMemsetAsync(cnts, 0, (size_t)G * 4, stream);

    // ---- CSR build: bucketed counting sort (dense writes throughout) ----
    histA_kernel <<<KNBLK, 256, 0, stream>>>(ei, counts, E, K, chunk);
    scanB1_kernel<<<K,     256, 0, stream>>>(counts, btot, K);
    scanB2_kernel<<<1,     256, 0, stream>>>(btot, bb0, K);
    passB_kernel <<<KNBLK, 256, 0, stream>>>(ei, ew, counts, bb0, ebuf, E, K, chunk);
    passC_kernel <<<K,     256, 0, stream>>>(ebuf, bb0, csr, offs, N, E, K);

    const int AGG_BLOCKS = (N * 16 + 255) / 256;

    // ---- 3 fused layers: agg (raw features) -> @W + b -> relu ----
    agg_fused_kernel<<<AGG_BLOCKS, 256, 0, stream>>>(x,    csr, offs, W1, b1, bufA, N);
    agg_fused_kernel<<<AGG_BLOCKS, 256, 0, stream>>>(bufA, csr, offs, W2, b2, bufB, N);
    agg_fused_kernel<<<AGG_BLOCKS, 256, 0, stream>>>(bufB, csr, offs, W3, b3, bufA, N);

    // ---- pool + head ----
    pool_kernel<<<1024, 256, 0, stream>>>(bufA, batch, sums, cnts, N);
    head_kernel<<<1, 256, 0, stream>>>(sums, cnts, lw1, lb1, lw2, lb2, lw3, lb3, out, G);
}